// Round 2
// baseline (389.741 us; speedup 1.0000x reference)
//
#include <hip/hip_runtime.h>
#include <cstdint>

#define BB 32768
#define II 1024
#define HH 1024
#define SPLIT 8
#define KCH (BB/SPLIT)

typedef _Float16 f16;
typedef _Float16 f16x4 __attribute__((ext_vector_type(4)));
typedef _Float16 f16x8 __attribute__((ext_vector_type(8)));
typedef float f32x4 __attribute__((ext_vector_type(4)));

__device__ __forceinline__ float tanh_fast(float s){
    float a = fabsf(s);
    float e = __expf(-2.0f * a);
    float t = __fdividef(1.0f - e, 1.0f + e);
    return s < 0.0f ? -t : t;
}

// GEMM1: hidden = tanh(x @ W).
// A = x [B][I] f32, k(=i)-contiguous -> row-major f16 stage.
// B = W [I][H] f32, k(=i)-strided    -> LDS-transposed f16 stage (W is L2-resident).
// Tile 128x128, BK=32, 4 waves.
__global__ __launch_bounds__(256) void k_gemm1(const float* __restrict__ x,
                                               const float* __restrict__ W,
                                               float* __restrict__ hidden){
    __shared__ f16 Al[128*40];
    __shared__ f16 Bl[128*40];
    const int t = threadIdx.x, lane = t & 63, wid = t >> 6;
    const int bm = (int)blockIdx.x >> 3, bn = (int)blockIdx.x & 7;
    const int wr = wid >> 1, wc = wid & 1;
    const int fr = lane & 15, kq = (lane >> 4) * 8;
    f32x4 acc[4][4] = {};
    for (int kb = 0; kb < II/32; ++kb){
        // A stage: x rows, k-contiguous, vector f16x4 writes
        #pragma unroll
        for (int p = 0; p < 4; ++p){
            int row = p*32 + (t>>3);
            int c4  = (t&7)*4;
            float4 v = *(const float4*)&x[(size_t)(bm*128+row)*II + kb*32 + c4];
            f16x4 hv = { (f16)v.x, (f16)v.y, (f16)v.z, (f16)v.w };
            *(f16x4*)&Al[row*40 + c4] = hv;
        }
        // B stage: W[k][n] -> Bl[n][k] (transpose in LDS)
        {
            int k = t >> 3;
            #pragma unroll
            for (int p = 0; p < 4; ++p){
                int col = p*32 + (t&7)*4;
                float4 v = *(const float4*)&W[(size_t)(kb*32+k)*HH + bn*128 + col];
                Bl[(col+0)*40 + k] = (f16)v.x;
                Bl[(col+1)*40 + k] = (f16)v.y;
                Bl[(col+2)*40 + k] = (f16)v.z;
                Bl[(col+3)*40 + k] = (f16)v.w;
            }
        }
        __syncthreads();
        f16x8 af[4], bf[4];
        #pragma unroll
        for (int m=0;m<4;++m) af[m] = *(const f16x8*)&Al[(wr*64+m*16+fr)*40 + kq];
        #pragma unroll
        for (int n=0;n<4;++n) bf[n] = *(const f16x8*)&Bl[(wc*64+n*16+fr)*40 + kq];
        #pragma unroll
        for (int m=0;m<4;++m)
            #pragma unroll
            for (int n=0;n<4;++n)
                acc[m][n] = __builtin_amdgcn_mfma_f32_16x16x32_f16(af[m], bf[n], acc[m][n], 0, 0, 0);
        __syncthreads();
    }
    #pragma unroll
    for (int m=0;m<4;++m){
        #pragma unroll
        for (int n=0;n<4;++n){
            int row0 = wr*64 + m*16 + ((lane>>4)<<2);
            int col  = wc*64 + n*16 + fr;
            #pragma unroll
            for (int q=0;q<4;++q)
                hidden[(size_t)(bm*128+row0+q)*HH + bn*128 + col] = tanh_fast(acc[m][n][q]);
        }
    }
}

// GEMM2: delta = x^T @ hidden, split-K over batch. Both operands k(=b)-strided
// in memory -> LDS-transpose stage both. Tile 128x128, BK=32, 4 waves.
__global__ __launch_bounds__(256) void k_gemm2(const float* __restrict__ x,
                                               const float* __restrict__ hidden,
                                               float* __restrict__ part){
    __shared__ f16 As[128*40];
    __shared__ f16 Bs[128*40];
    const int t = threadIdx.x, lane = t & 63, wid = t >> 6;
    const int tile = (int)blockIdx.x & 63, split = (int)blockIdx.x >> 6;
    const int bm = tile & 7, bn = tile >> 3;
    const int wr = wid >> 1, wc = wid & 1;
    const int ks = split * KCH;
    const int fr = lane & 15, kq = (lane >> 4) * 8;
    f32x4 acc[4][4] = {};
    for (int kb = 0; kb < KCH/32; ++kb){
        const int k = t >> 3;
        const int b = ks + kb*32 + k;
        // A stage: x[b][i] -> As[i][k]
        #pragma unroll
        for (int p = 0; p < 4; ++p){
            int col = p*32 + (t&7)*4;
            float4 v = *(const float4*)&x[(size_t)b*II + bm*128 + col];
            As[(col+0)*40 + k] = (f16)v.x;
            As[(col+1)*40 + k] = (f16)v.y;
            As[(col+2)*40 + k] = (f16)v.z;
            As[(col+3)*40 + k] = (f16)v.w;
        }
        // B stage: hidden[b][h] -> Bs[h][k]
        #pragma unroll
        for (int p = 0; p < 4; ++p){
            int col = p*32 + (t&7)*4;
            float4 v = *(const float4*)&hidden[(size_t)b*HH + bn*128 + col];
            Bs[(col+0)*40 + k] = (f16)v.x;
            Bs[(col+1)*40 + k] = (f16)v.y;
            Bs[(col+2)*40 + k] = (f16)v.z;
            Bs[(col+3)*40 + k] = (f16)v.w;
        }
        __syncthreads();
        f16x8 af[4], bf[4];
        #pragma unroll
        for (int m=0;m<4;++m) af[m] = *(const f16x8*)&As[(wr*64+m*16+fr)*40 + kq];
        #pragma unroll
        for (int n=0;n<4;++n) bf[n] = *(const f16x8*)&Bs[(wc*64+n*16+fr)*40 + kq];
        #pragma unroll
        for (int m=0;m<4;++m)
            #pragma unroll
            for (int n=0;n<4;++n)
                acc[m][n] = __builtin_amdgcn_mfma_f32_16x16x32_f16(af[m], bf[n], acc[m][n], 0, 0, 0);
        __syncthreads();
    }
    #pragma unroll
    for (int m=0;m<4;++m){
        #pragma unroll
        for (int n=0;n<4;++n){
            int row0 = wr*64 + m*16 + ((lane>>4)<<2);
            int col  = wc*64 + n*16 + fr;
            #pragma unroll
            for (int q=0;q<4;++q)
                part[(size_t)split*1048576 + (size_t)(bm*128+row0+q)*HH + bn*128 + col] = acc[m][n][q];
        }
    }
}

__global__ __launch_bounds__(256) void k_final(const float* __restrict__ part,
                                               const float* __restrict__ W,
                                               float* __restrict__ outW){
    const int i = blockIdx.x*256 + threadIdx.x;
    const size_t o = (size_t)i*4;
    float sx=0.f, sy=0.f, sz=0.f, sw=0.f;
    #pragma unroll
    for (int sp=0; sp<SPLIT; ++sp){
        float4 p = *(const float4*)&part[(size_t)sp*1048576 + o];
        sx += p.x; sy += p.y; sz += p.z; sw += p.w;
    }
    const float SCALE = 3.0517578125e-07f;  // 0.01 / 32768
    float4 w = *(const float4*)&W[o];
    float4 r;
    r.x = fminf(1.f, fmaxf(-1.f, fmaf(SCALE, sx, w.x)));
    r.y = fminf(1.f, fmaxf(-1.f, fmaf(SCALE, sy, w.y)));
    r.z = fminf(1.f, fmaxf(-1.f, fmaf(SCALE, sz, w.z)));
    r.w = fminf(1.f, fmaxf(-1.f, fmaf(SCALE, sw, w.w)));
    *(float4*)&outW[o] = r;
}

extern "C" void kernel_launch(void* const* d_in, const int* in_sizes, int n_in,
                              void* d_out, int out_size, void* d_ws, size_t ws_size,
                              hipStream_t stream){
    (void)in_sizes; (void)n_in; (void)out_size; (void)ws_size;
    const float* x = (const float*)d_in[0];
    const float* W = (const float*)d_in[1];
    float* hidden = (float*)d_out;
    float* outW   = hidden + (size_t)BB*HH;
    float* part   = (float*)d_ws;   // f32 [SPLIT][1024][1024] = 32 MB total

    k_gemm1<<<dim3((BB/128)*(HH/128)), 256, 0, stream>>>(x, W, hidden);
    k_gemm2<<<dim3(64*SPLIT), 256, 0, stream>>>(x, hidden, part);
    k_final<<<dim3((II*HH)/(256*4)), 256, 0, stream>>>(part, W, outW);
}

// Round 3
// 387.573 us; speedup vs baseline: 1.0056x; 1.0056x over previous
//
#include <hip/hip_runtime.h>
#include <cstdint>

#define BB 32768
#define II 1024
#define HH 1024
#define SPLIT 8
#define KCH (BB/SPLIT)

typedef _Float16 f16;
typedef _Float16 f16x4 __attribute__((ext_vector_type(4)));
typedef _Float16 f16x8 __attribute__((ext_vector_type(8)));
typedef float f32x4 __attribute__((ext_vector_type(4)));

typedef const __attribute__((address_space(1))) void gvoid_t;
typedef __attribute__((address_space(3))) void lvoid_t;

__device__ __forceinline__ void gload16(const void* g, void* l){
    __builtin_amdgcn_global_load_lds((gvoid_t*)g, (lvoid_t*)l, 16, 0, 0);
}

__device__ __forceinline__ float tanh_fast(float s){
    float a = fabsf(s);
    float e = __expf(-2.0f * a);
    float t = __fdividef(1.0f - e, 1.0f + e);
    return s < 0.0f ? -t : t;
}

// ---------------- Tier A kernels ----------------

// in [R][C] f32 -> cvt_out [R][C] f16 (optional) + tr_out [C][R] f16.
// 64x64 tiles; LDS f32 pad 67 (2-way conflicts max).
__global__ __launch_bounds__(256) void k_prep(const float* __restrict__ in,
                                              f16* __restrict__ cvt_out,
                                              f16* __restrict__ tr_out,
                                              int C, int R){
    __shared__ float lt[64*67];
    const int t = threadIdx.x;
    const int r0 = blockIdx.x*64, c0 = blockIdx.y*64;
    #pragma unroll
    for (int p=0; p<4; ++p){
        int r = p*16 + (t>>4);
        int c = (t&15)*4;
        float4 v = *(const float4*)&in[(size_t)(r0+r)*C + c0 + c];
        if (cvt_out){
            f16x4 hv = {(f16)v.x,(f16)v.y,(f16)v.z,(f16)v.w};
            *(f16x4*)&cvt_out[(size_t)(r0+r)*C + c0 + c] = hv;
        }
        lt[r*67 + c+0] = v.x;
        lt[r*67 + c+1] = v.y;
        lt[r*67 + c+2] = v.z;
        lt[r*67 + c+3] = v.w;
    }
    __syncthreads();
    const int c = t>>2, rb = (t&3)*16;
    f16x8 a, b;
    #pragma unroll
    for (int e=0; e<8; ++e) a[e] = (f16)lt[(rb+e)*67 + c];
    #pragma unroll
    for (int e=0; e<8; ++e) b[e] = (f16)lt[(rb+8+e)*67 + c];
    f16* o = &tr_out[(size_t)(c0+c)*R + r0 + rb];
    *(f16x8*)o = a;
    *(f16x8*)(o+8) = b;
}

// GEMM1 (transposed form): D[h][b] = sum_i wt[h][i]*xf[b][i]; hidden = tanh(D)^T.
// Both operands f16 k-major -> global_load_lds(16B), linear LDS [128][32]. BK=32.
__global__ __launch_bounds__(256) void k_gemm1t(const f16* __restrict__ wt,
                                                const f16* __restrict__ xf,
                                                float* __restrict__ hidden,
                                                f16* __restrict__ ht){
    __shared__ char smem[34816];           // K-loop: As+Bs = 16KB; epilogue: Cl[128][136] f16
    f16* As = (f16*)smem;                  // [128][32] wt rows (h)
    f16* Bs = (f16*)(smem + 8192);         // [128][32] xf rows (b)
    const int t = threadIdx.x, lane = t & 63, wid = t >> 6;
    const int bm = (int)blockIdx.x & 7;    // h tile (A-panel reused by consecutive blocks)
    const int bn = (int)blockIdx.x >> 3;   // b tile
    const int wr = wid >> 1, wc = wid & 1;
    const int fr = lane & 15, kq = (lane >> 4) * 8;
    const int srow = lane >> 2, sch = (lane & 3) * 8;
    f32x4 acc[4][4] = {};
    for (int kb = 0; kb < II/32; ++kb){
        #pragma unroll
        for (int ii=0; ii<2; ++ii){
            int i = wid*2 + ii;
            int row = i*16 + srow;
            gload16(&wt[(size_t)(bm*128+row)*II + kb*32 + sch], &As[i*512]);
            gload16(&xf[(size_t)(bn*128+row)*II + kb*32 + sch], &Bs[i*512]);
        }
        __syncthreads();
        f16x8 af[4], bf[4];
        #pragma unroll
        for (int m=0;m<4;++m) af[m] = *(const f16x8*)&As[(wr*64+m*16+fr)*32 + kq];
        #pragma unroll
        for (int n=0;n<4;++n) bf[n] = *(const f16x8*)&Bs[(wc*64+n*16+fr)*32 + kq];
        #pragma unroll
        for (int m=0;m<4;++m)
            #pragma unroll
            for (int n=0;n<4;++n)
                acc[m][n] = __builtin_amdgcn_mfma_f32_16x16x32_f16(af[m], bf[n], acc[m][n], 0, 0, 0);
        __syncthreads();
    }
    // Epilogue: tanh once, bounce through LDS as f16 [b][h] (pad 136).
    f16* Cl = (f16*)smem;
    #pragma unroll
    for (int m=0;m<4;++m){
        #pragma unroll
        for (int n=0;n<4;++n){
            int bl = wc*64 + n*16 + fr;
            int h0 = wr*64 + m*16 + ((lane>>4)<<2);
            #pragma unroll
            for (int q=0;q<4;++q)
                Cl[bl*136 + h0 + q] = (f16)tanh_fast(acc[m][n][q]);
        }
    }
    __syncthreads();
    // hidden f32 [b][h]: coalesced float4 stores
    #pragma unroll
    for (int p=0;p<4;++p){
        int b = p*32 + (t>>3);
        int hoff = (t&7)*16;
        const f16x4* cp = (const f16x4*)&Cl[b*136 + hoff];
        float* hp = &hidden[(size_t)(bn*128+b)*HH + bm*128 + hoff];
        #pragma unroll
        for (int j=0;j<4;++j){
            f16x4 hv = cp[j];
            float4 o = {(float)hv[0],(float)hv[1],(float)hv[2],(float)hv[3]};
            *(float4*)(hp + j*4) = o;
        }
    }
    // ht f16 [h][b]: coalesced f16x8 stores
    #pragma unroll
    for (int p=0;p<4;++p){
        int h = p*32 + (t>>3);
        int boff = (t&7)*16;
        f16x8 a, b2;
        #pragma unroll
        for (int j=0;j<8;++j) a[j]  = Cl[(boff+j)*136 + h];
        #pragma unroll
        for (int j=0;j<8;++j) b2[j] = Cl[(boff+8+j)*136 + h];
        f16* o = &ht[(size_t)(bm*128+h)*BB + bn*128 + boff];
        *(f16x8*)o = a;
        *(f16x8*)(o+8) = b2;
    }
}

// GEMM2: part[split] += xt[i][b] * ht[h][b] over b-chunk. m97 structure, split-K=8.
__global__ __launch_bounds__(256) void k_gemm2f(const f16* __restrict__ xt,
                                                const f16* __restrict__ ht,
                                                float* __restrict__ part){
    __shared__ f16 smem2[8192];            // As[128][32] + Bs[128][32]
    f16* As = smem2;
    f16* Bs = smem2 + 4096;
    const int t = threadIdx.x, lane = t & 63, wid = t >> 6;
    const int tile = (int)blockIdx.x & 63, split = (int)blockIdx.x >> 6;
    const int bm = tile & 7, bn = tile >> 3;
    const int wr = wid >> 1, wc = wid & 1;
    const int ks = split * KCH;
    const int fr = lane & 15, kq = (lane >> 4) * 8;
    const int srow = lane >> 2, sch = (lane & 3) * 8;
    f32x4 acc[4][4] = {};
    for (int kb = 0; kb < KCH/32; ++kb){
        #pragma unroll
        for (int ii=0; ii<2; ++ii){
            int i = wid*2 + ii;
            int row = i*16 + srow;
            gload16(&xt[(size_t)(bm*128+row)*BB + ks + kb*32 + sch], &As[i*512]);
            gload16(&ht[(size_t)(bn*128+row)*BB + ks + kb*32 + sch], &Bs[i*512]);
        }
        __syncthreads();
        f16x8 af[4], bf[4];
        #pragma unroll
        for (int m=0;m<4;++m) af[m] = *(const f16x8*)&As[(wr*64+m*16+fr)*32 + kq];
        #pragma unroll
        for (int n=0;n<4;++n) bf[n] = *(const f16x8*)&Bs[(wc*64+n*16+fr)*32 + kq];
        #pragma unroll
        for (int m=0;m<4;++m)
            #pragma unroll
            for (int n=0;n<4;++n)
                acc[m][n] = __builtin_amdgcn_mfma_f32_16x16x32_f16(af[m], bf[n], acc[m][n], 0, 0, 0);
        __syncthreads();
    }
    #pragma unroll
    for (int m=0;m<4;++m){
        #pragma unroll
        for (int n=0;n<4;++n){
            int row0 = wr*64 + m*16 + ((lane>>4)<<2);
            int col  = wc*64 + n*16 + fr;
            #pragma unroll
            for (int q=0;q<4;++q)
                part[(size_t)split*1048576 + (size_t)(bm*128+row0+q)*HH + bn*128 + col] = acc[m][n][q];
        }
    }
}

__global__ __launch_bounds__(256) void k_final(const float* __restrict__ part,
                                               const float* __restrict__ W,
                                               float* __restrict__ outW){
    const int i = blockIdx.x*256 + threadIdx.x;
    const size_t o = (size_t)i*4;
    float sx=0.f, sy=0.f, sz=0.f, sw=0.f;
    #pragma unroll
    for (int sp=0; sp<SPLIT; ++sp){
        float4 p = *(const float4*)&part[(size_t)sp*1048576 + o];
        sx += p.x; sy += p.y; sz += p.z; sw += p.w;
    }
    const float SCALE = 3.0517578125e-07f;  // 0.01 / 32768
    float4 w = *(const float4*)&W[o];
    float4 r;
    r.x = fminf(1.f, fmaxf(-1.f, fmaf(SCALE, sx, w.x)));
    r.y = fminf(1.f, fmaxf(-1.f, fmaf(SCALE, sy, w.y)));
    r.z = fminf(1.f, fmaxf(-1.f, fmaf(SCALE, sz, w.z)));
    r.w = fminf(1.f, fmaxf(-1.f, fmaf(SCALE, sw, w.w)));
    *(float4*)&outW[o] = r;
}

// ---------------- Tier B fallback (round-2, passing) ----------------

__global__ __launch_bounds__(256) void k_gemm1_fb(const float* __restrict__ x,
                                                  const float* __restrict__ W,
                                                  float* __restrict__ hidden){
    __shared__ f16 Al[128*40];
    __shared__ f16 Bl[128*40];
    const int t = threadIdx.x, lane = t & 63, wid = t >> 6;
    const int bm = (int)blockIdx.x >> 3, bn = (int)blockIdx.x & 7;
    const int wr = wid >> 1, wc = wid & 1;
    const int fr = lane & 15, kq = (lane >> 4) * 8;
    f32x4 acc[4][4] = {};
    for (int kb = 0; kb < II/32; ++kb){
        #pragma unroll
        for (int p = 0; p < 4; ++p){
            int row = p*32 + (t>>3);
            int c4  = (t&7)*4;
            float4 v = *(const float4*)&x[(size_t)(bm*128+row)*II + kb*32 + c4];
            f16x4 hv = { (f16)v.x, (f16)v.y, (f16)v.z, (f16)v.w };
            *(f16x4*)&Al[row*40 + c4] = hv;
        }
        {
            int k = t >> 3;
            #pragma unroll
            for (int p = 0; p < 4; ++p){
                int col = p*32 + (t&7)*4;
                float4 v = *(const float4*)&W[(size_t)(kb*32+k)*HH + bn*128 + col];
                Bl[(col+0)*40 + k] = (f16)v.x;
                Bl[(col+1)*40 + k] = (f16)v.y;
                Bl[(col+2)*40 + k] = (f16)v.z;
                Bl[(col+3)*40 + k] = (f16)v.w;
            }
        }
        __syncthreads();
        f16x8 af[4], bf[4];
        #pragma unroll
        for (int m=0;m<4;++m) af[m] = *(const f16x8*)&Al[(wr*64+m*16+fr)*40 + kq];
        #pragma unroll
        for (int n=0;n<4;++n) bf[n] = *(const f16x8*)&Bl[(wc*64+n*16+fr)*40 + kq];
        #pragma unroll
        for (int m=0;m<4;++m)
            #pragma unroll
            for (int n=0;n<4;++n)
                acc[m][n] = __builtin_amdgcn_mfma_f32_16x16x32_f16(af[m], bf[n], acc[m][n], 0, 0, 0);
        __syncthreads();
    }
    #pragma unroll
    for (int m=0;m<4;++m){
        #pragma unroll
        for (int n=0;n<4;++n){
            int row0 = wr*64 + m*16 + ((lane>>4)<<2);
            int col  = wc*64 + n*16 + fr;
            #pragma unroll
            for (int q=0;q<4;++q)
                hidden[(size_t)(bm*128+row0+q)*HH + bn*128 + col] = tanh_fast(acc[m][n][q]);
        }
    }
}

__global__ __launch_bounds__(256) void k_gemm2_fb(const float* __restrict__ x,
                                                  const float* __restrict__ hidden,
                                                  float* __restrict__ part){
    __shared__ f16 As[128*40];
    __shared__ f16 Bs[128*40];
    const int t = threadIdx.x, lane = t & 63, wid = t >> 6;
    const int tile = (int)blockIdx.x & 63, split = (int)blockIdx.x >> 6;
    const int bm = tile & 7, bn = tile >> 3;
    const int wr = wid >> 1, wc = wid & 1;
    const int ks = split * KCH;
    const int fr = lane & 15, kq = (lane >> 4) * 8;
    f32x4 acc[4][4] = {};
    for (int kb = 0; kb < KCH/32; ++kb){
        const int k = t >> 3;
        const int b = ks + kb*32 + k;
        #pragma unroll
        for (int p = 0; p < 4; ++p){
            int col = p*32 + (t&7)*4;
            float4 v = *(const float4*)&x[(size_t)b*II + bm*128 + col];
            As[(col+0)*40 + k] = (f16)v.x;
            As[(col+1)*40 + k] = (f16)v.y;
            As[(col+2)*40 + k] = (f16)v.z;
            As[(col+3)*40 + k] = (f16)v.w;
        }
        #pragma unroll
        for (int p = 0; p < 4; ++p){
            int col = p*32 + (t&7)*4;
            float4 v = *(const float4*)&hidden[(size_t)b*HH + bn*128 + col];
            Bs[(col+0)*40 + k] = (f16)v.x;
            Bs[(col+1)*40 + k] = (f16)v.y;
            Bs[(col+2)*40 + k] = (f16)v.z;
            Bs[(col+3)*40 + k] = (f16)v.w;
        }
        __syncthreads();
        f16x8 af[4], bf[4];
        #pragma unroll
        for (int m=0;m<4;++m) af[m] = *(const f16x8*)&As[(wr*64+m*16+fr)*40 + kq];
        #pragma unroll
        for (int n=0;n<4;++n) bf[n] = *(const f16x8*)&Bs[(wc*64+n*16+fr)*40 + kq];
        #pragma unroll
        for (int m=0;m<4;++m)
            #pragma unroll
            for (int n=0;n<4;++n)
                acc[m][n] = __builtin_amdgcn_mfma_f32_16x16x32_f16(af[m], bf[n], acc[m][n], 0, 0, 0);
        __syncthreads();
    }
    #pragma unroll
    for (int m=0;m<4;++m){
        #pragma unroll
        for (int n=0;n<4;++n){
            int row0 = wr*64 + m*16 + ((lane>>4)<<2);
            int col  = wc*64 + n*16 + fr;
            #pragma unroll
            for (int q=0;q<4;++q)
                part[(size_t)split*1048576 + (size_t)(bm*128+row0+q)*HH + bn*128 + col] = acc[m][n][q];
        }
    }
}

extern "C" void kernel_launch(void* const* d_in, const int* in_sizes, int n_in,
                              void* d_out, int out_size, void* d_ws, size_t ws_size,
                              hipStream_t stream){
    (void)in_sizes; (void)n_in; (void)out_size;
    const float* x = (const float*)d_in[0];
    const float* W = (const float*)d_in[1];
    float* hidden = (float*)d_out;
    float* outW   = hidden + (size_t)BB*HH;
    char* ws = (char*)d_ws;

    // Tier A ws layout: xf f16 [B][I] @0 (64MB) | xt f16 [I][B] @64M | ht f16 [H][B] @128M |
    //                   wt f16 [H][I] @192M (2MB) | part f32 [8][I][H] @0 (overlaps dead xf)
    const size_t NEED_A = 203423744ull;  // 194 MB
    if (ws_size >= NEED_A){
        f16*   xf   = (f16*)(ws);
        f16*   xt   = (f16*)(ws + 67108864ull);
        f16*   ht   = (f16*)(ws + 134217728ull);
        f16*   wt   = (f16*)(ws + 201326592ull);
        float* part = (float*)(ws);          // reuses xf region after gemm1t
        k_prep<<<dim3(BB/64, II/64), 256, 0, stream>>>(x, xf, xt, II, BB);
        k_prep<<<dim3(II/64, HH/64), 256, 0, stream>>>(W, nullptr, wt, HH, II);
        k_gemm1t<<<dim3((HH/128)*(BB/128)), 256, 0, stream>>>(wt, xf, hidden, ht);
        k_gemm2f<<<dim3(64*SPLIT), 256, 0, stream>>>(xt, ht, part);
        k_final<<<dim3((II*HH)/1024), 256, 0, stream>>>(part, W, outW);
    } else {
        float* part = (float*)ws;            // 32 MB (proven available in round 2)
        k_gemm1_fb<<<dim3((BB/128)*(HH/128)), 256, 0, stream>>>(x, W, hidden);
        k_gemm2_fb<<<dim3(64*SPLIT), 256, 0, stream>>>(x, hidden, part);
        k_final<<<dim3((II*HH)/1024), 256, 0, stream>>>(part, W, outW);
    }
}

// Round 4
// 281.526 us; speedup vs baseline: 1.3844x; 1.3767x over previous
//
#include <hip/hip_runtime.h>
#include <cstdint>

#define BB 32768
#define II 1024
#define HH 1024
#define SPLIT 16
#define KCH (BB/SPLIT)      // 2048
#define NT1 (II/64)         // 16 K-tiles (gemm1)
#define NT2 (KCH/64)        // 32 K-tiles per split (gemm2)

typedef _Float16 f16;
typedef _Float16 f16x4 __attribute__((ext_vector_type(4)));
typedef _Float16 f16x8 __attribute__((ext_vector_type(8)));
typedef float f32x4 __attribute__((ext_vector_type(4)));

typedef const __attribute__((address_space(1))) void gvoid_t;
typedef __attribute__((address_space(3))) void lvoid_t;

__device__ __forceinline__ void gload16(const void* g, void* l){
    __builtin_amdgcn_global_load_lds((gvoid_t*)g, (lvoid_t*)l, 16, 0, 0);
}

__device__ __forceinline__ float tanh_fast(float s){
    float a = fabsf(s);
    float e = __expf(-2.0f * a);
    float t = __fdividef(1.0f - e, 1.0f + e);
    return s < 0.0f ? -t : t;
}

// in [R][C] f32 -> cvt_out [R][C] f16 (optional) + tr_out [C][R] f16. 64x64 tiles.
__global__ __launch_bounds__(256) void k_prep(const float* __restrict__ in,
                                              f16* __restrict__ cvt_out,
                                              f16* __restrict__ tr_out,
                                              int C, int R){
    __shared__ float lt[64*67];
    const int t = threadIdx.x;
    const int r0 = blockIdx.x*64, c0 = blockIdx.y*64;
    #pragma unroll
    for (int p=0; p<4; ++p){
        int r = p*16 + (t>>4);
        int c = (t&15)*4;
        float4 v = *(const float4*)&in[(size_t)(r0+r)*C + c0 + c];
        if (cvt_out){
            f16x4 hv = {(f16)v.x,(f16)v.y,(f16)v.z,(f16)v.w};
            *(f16x4*)&cvt_out[(size_t)(r0+r)*C + c0 + c] = hv;
        }
        lt[r*67 + c+0] = v.x;
        lt[r*67 + c+1] = v.y;
        lt[r*67 + c+2] = v.z;
        lt[r*67 + c+3] = v.w;
    }
    __syncthreads();
    const int c = t>>2, rb = (t&3)*16;
    f16x8 a, b;
    #pragma unroll
    for (int e=0; e<8; ++e) a[e] = (f16)lt[(rb+e)*67 + c];
    #pragma unroll
    for (int e=0; e<8; ++e) b[e] = (f16)lt[(rb+8+e)*67 + c];
    f16* o = &tr_out[(size_t)(c0+c)*R + r0 + rb];
    *(f16x8*)o = a;
    *(f16x8*)(o+8) = b;
}

// stage one 128x64-f16 half-tile (16KB) into linear LDS with inverse-swizzled source.
// Swizzle S(b) = b ^ (((b>>9)&1)<<5); here bit9 of b depends only on lane -> XOR (lane&32).
__device__ __forceinline__ void stage_half(const f16* __restrict__ panel, int ld,
                                           int row0, int kcol0, char* lds_half,
                                           int wid, int lane){
    #pragma unroll
    for (int r=0;r<2;++r){
        int b  = r*8192 + wid*1024 + lane*16;
        int sb = b ^ (lane & 32);
        const f16* src = panel + (size_t)(row0 + (sb>>7))*ld + kcol0 + ((sb&127)>>1);
        gload16(src, lds_half + r*8192 + wid*1024);
    }
}

#define RD_A(BUFA, mh) { \
    _Pragma("unroll") for (int m_=0;m_<4;++m_){ \
      _Pragma("unroll") for (int ks_=0;ks_<2;++ks_){ \
        af[m_][ks_] = *(const f16x8*)((BUFA) + laneA + (mh)*8192 + m_*2048 + ks_*64); }}}

#define RD_B(BUFB, nh) { \
    _Pragma("unroll") for (int n_=0;n_<2;++n_){ \
      _Pragma("unroll") for (int ks_=0;ks_<2;++ks_){ \
        bf[(nh)*2+n_][ks_] = *(const f16x8*)((BUFB) + laneB + (nh)*4096 + n_*2048 + ks_*64); }}}

#define MFMA_Q(mh,nh) { \
    __builtin_amdgcn_s_setprio(1); \
    _Pragma("unroll") for (int m_=0;m_<4;++m_){ \
      _Pragma("unroll") for (int n_=0;n_<2;++n_){ \
        _Pragma("unroll") for (int ks_=0;ks_<2;++ks_){ \
          acc[(mh)*4+m_][(nh)*2+n_] = __builtin_amdgcn_mfma_f32_16x16x32_f16( \
              af[m_][ks_], bf[(nh)*2+n_][ks_], acc[(mh)*4+m_][(nh)*2+n_], 0,0,0); }}} \
    __builtin_amdgcn_s_setprio(0); }

#define PH_SYNC1 { __builtin_amdgcn_s_barrier(); \
    asm volatile("s_waitcnt lgkmcnt(0)" ::: "memory"); \
    __builtin_amdgcn_sched_barrier(0); }
#define PH_SYNC2 { __builtin_amdgcn_s_barrier(); }

// 256x256 tile, BK=64, 8 waves, 8-phase pipelined K-loop (T2+T3+T4+T5).
__device__ __forceinline__ void kloop8(const f16* __restrict__ Ap, int lda, int arow0,
                                       const f16* __restrict__ Bp, int ldb, int brow0,
                                       int kbase, int nt, char* sm,
                                       f32x4 (&acc)[8][4])
{
    const int t = threadIdx.x, lane = t & 63, wid = t >> 6;
    const int wr = wid >> 2, wc = wid & 3;
    const int fr = lane & 15, kg = lane >> 4;
    const int mask = nt - 1;
    char* const A0 = sm;
    char* const B0 = sm + 32768;
    char* const A1 = sm + 65536;
    char* const B1 = sm + 98304;
    const int laneA = wr*16384 + fr*128 + ((kg*16) ^ ((fr&4)<<3));
    const int laneB = (wc>>1)*16384 + (wc&1)*8192 + fr*128 + ((kg*16) ^ ((fr&4)<<3));

    f16x8 af[4][2], bf[4][2];

    // prologue: K0 -> buf0 (all 4 half-tiles), K1 -> B1 half0, A1 half0
    stage_half(Ap, lda, arow0 +   0, kbase +  0, A0,         wid, lane);
    stage_half(Ap, lda, arow0 + 128, kbase +  0, A0 + 16384, wid, lane);
    stage_half(Bp, ldb, brow0 +   0, kbase +  0, B0,         wid, lane);
    stage_half(Bp, ldb, brow0 + 128, kbase +  0, B0 + 16384, wid, lane);
    stage_half(Bp, ldb, brow0 +   0, kbase + 64, B1,         wid, lane);
    stage_half(Ap, lda, arow0 +   0, kbase + 64, A1,         wid, lane);
    asm volatile("s_waitcnt vmcnt(4)" ::: "memory");
    __builtin_amdgcn_s_barrier();

    const int ni = nt >> 1;
    for (int it = 0; it < ni; ++it){
        const int k1 = (2*it + 1) * 64;
        const int k2 = ((2*it + 2) & mask) * 64;
        const int k3 = ((2*it + 3) & mask) * 64;
        // phase 1: Q(0,0) from buf0; stage A1 half1 (k1)
        RD_A(A0, 0); RD_B(B0, 0);
        stage_half(Ap, lda, arow0 + 128, kbase + k1, A1 + 16384, wid, lane);
        PH_SYNC1; MFMA_Q(0,0); PH_SYNC2;
        // phase 2: Q(0,1); stage B1 half1 (k1)
        RD_B(B0, 1);
        stage_half(Bp, ldb, brow0 + 128, kbase + k1, B1 + 16384, wid, lane);
        PH_SYNC1; MFMA_Q(0,1); PH_SYNC2;
        // phase 3: Q(1,0); stage B0 half0 (k2)
        RD_A(A0, 1);
        stage_half(Bp, ldb, brow0 +   0, kbase + k2, B0, wid, lane);
        PH_SYNC1; MFMA_Q(1,0); PH_SYNC2;
        // phase 4: Q(1,1); stage A0 half0 (k2); counted vmcnt
        stage_half(Ap, lda, arow0 +   0, kbase + k2, A0, wid, lane);
        PH_SYNC1; MFMA_Q(1,1);
        asm volatile("s_waitcnt vmcnt(4)" ::: "memory");
        __builtin_amdgcn_s_barrier();
        // phase 5: Q(0,0) from buf1; stage A0 half1 (k2)
        RD_A(A1, 0); RD_B(B1, 0);
        stage_half(Ap, lda, arow0 + 128, kbase + k2, A0 + 16384, wid, lane);
        PH_SYNC1; MFMA_Q(0,0); PH_SYNC2;
        // phase 6: Q(0,1); stage B0 half1 (k2)
        RD_B(B1, 1);
        stage_half(Bp, ldb, brow0 + 128, kbase + k2, B0 + 16384, wid, lane);
        PH_SYNC1; MFMA_Q(0,1); PH_SYNC2;
        // phase 7: Q(1,0); stage B1 half0 (k3)
        RD_A(A1, 1);
        stage_half(Bp, ldb, brow0 +   0, kbase + k3, B1, wid, lane);
        PH_SYNC1; MFMA_Q(1,0); PH_SYNC2;
        // phase 8: Q(1,1); stage A1 half0 (k3); counted vmcnt
        stage_half(Ap, lda, arow0 +   0, kbase + k3, A1, wid, lane);
        PH_SYNC1; MFMA_Q(1,1);
        asm volatile("s_waitcnt vmcnt(4)" ::: "memory");
        __builtin_amdgcn_s_barrier();
    }
    asm volatile("s_waitcnt vmcnt(0)" ::: "memory");
    __builtin_amdgcn_s_barrier();
}

// GEMM1: D[h][b] = sum_i wt[h][i]*xf[b][i]; hidden[b][h]=tanh(D), ht[h][b]=f16(tanh(D))
__global__ __launch_bounds__(512,2) void k_gemm1t8(const f16* __restrict__ wt,
                                                   const f16* __restrict__ xf,
                                                   float* __restrict__ hidden,
                                                   f16* __restrict__ ht){
    __shared__ char sm[131072];
    const int bm = (int)blockIdx.x & 3;    // h tile
    const int bn = (int)blockIdx.x >> 2;   // b tile
    f32x4 acc[8][4] = {};
    kloop8(wt, II, bm*256, xf, II, bn*256, 0, NT1, sm, acc);

    const int t = threadIdx.x, lane = t & 63, wid = t >> 6;
    const int wr = wid >> 2, wc = wid & 3;
    const int fr = lane & 15, kg = lane >> 4;
    const int h0 = bm*256, b0 = bn*256;
    f16* Cl = (f16*)sm;                    // [64 cols][264 pitch] per pass
    #pragma unroll
    for (int p=0; p<4; ++p){
        #pragma unroll
        for (int mf=0; mf<8; ++mf){
            f16x4 hv;
            #pragma unroll
            for (int q=0;q<4;++q) hv[q] = (f16)tanh_fast(acc[mf][p][q]);
            *(f16x4*)&Cl[(wc*16+fr)*264 + wr*128 + mf*16 + kg*4] = hv;
            #pragma unroll
            for (int q=0;q<4;++q)
                ht[(size_t)(h0 + wr*128 + mf*16 + kg*4 + q)*BB + b0 + wc*64 + p*16 + fr] = hv[q];
        }
        __syncthreads();
        {
            const int rl = t>>3, ci = t&7;
            const size_t hrow = (size_t)(b0 + (rl>>4)*64 + p*16 + (rl&15))*HH + h0 + ci*32;
            #pragma unroll
            for (int j=0;j<4;++j){
                f16x8 v = *(const f16x8*)&Cl[rl*264 + ci*32 + j*8];
                float4 o0 = {(float)v[0],(float)v[1],(float)v[2],(float)v[3]};
                float4 o1 = {(float)v[4],(float)v[5],(float)v[6],(float)v[7]};
                *(float4*)&hidden[hrow + j*8]     = o0;
                *(float4*)&hidden[hrow + j*8 + 4] = o1;
            }
        }
        __syncthreads();
    }
}

// GEMM2: part[split][i][h] = sum_{b in chunk} xt[i][b]*ht[h][b]
__global__ __launch_bounds__(512,2) void k_gemm2_8(const f16* __restrict__ xt,
                                                   const f16* __restrict__ ht,
                                                   float* __restrict__ part){
    __shared__ char sm[131072];
    const int tile = (int)blockIdx.x & 15, split = (int)blockIdx.x >> 4;
    const int bm = tile & 3, bn = tile >> 2;
    f32x4 acc[8][4] = {};
    kloop8(xt, BB, bm*256, ht, BB, bn*256, split*KCH, NT2, sm, acc);

    const int t = threadIdx.x, lane = t & 63, wid = t >> 6;
    const int wr = wid >> 2, wc = wid & 3;
    const int fr = lane & 15, kg = lane >> 4;
    const size_t pb = (size_t)split*II*HH;
    #pragma unroll
    for (int mf=0; mf<8; ++mf){
        const int i0 = bm*256 + wr*128 + mf*16 + kg*4;
        #pragma unroll
        for (int nf=0; nf<4; ++nf){
            const int h = bn*256 + wc*64 + nf*16 + fr;
            #pragma unroll
            for (int q=0;q<4;++q)
                part[pb + (size_t)(i0+q)*HH + h] = acc[mf][nf][q];
        }
    }
}

__global__ __launch_bounds__(256) void k_final(const float* __restrict__ part,
                                               const float* __restrict__ W,
                                               float* __restrict__ outW){
    const int i = blockIdx.x*256 + threadIdx.x;
    const size_t o = (size_t)i*4;
    float sx=0.f, sy=0.f, sz=0.f, sw=0.f;
    #pragma unroll
    for (int sp=0; sp<SPLIT; ++sp){
        float4 p = *(const float4*)&part[(size_t)sp*1048576 + o];
        sx += p.x; sy += p.y; sz += p.z; sw += p.w;
    }
    const float SCALE = 3.0517578125e-07f;  // 0.01 / 32768
    float4 w = *(const float4*)&W[o];
    float4 r;
    r.x = fminf(1.f, fmaxf(-1.f, fmaf(SCALE, sx, w.x)));
    r.y = fminf(1.f, fmaxf(-1.f, fmaf(SCALE, sy, w.y)));
    r.z = fminf(1.f, fmaxf(-1.f, fmaf(SCALE, sz, w.z)));
    r.w = fminf(1.f, fmaxf(-1.f, fmaf(SCALE, sw, w.w)));
    *(float4*)&outW[o] = r;
}

extern "C" void kernel_launch(void* const* d_in, const int* in_sizes, int n_in,
                              void* d_out, int out_size, void* d_ws, size_t ws_size,
                              hipStream_t stream){
    (void)in_sizes; (void)n_in; (void)out_size; (void)ws_size;
    const float* x = (const float*)d_in[0];
    const float* W = (const float*)d_in[1];
    float* hidden = (float*)d_out;
    float* outW   = hidden + (size_t)BB*HH;
    char* ws = (char*)d_ws;
    // ws: xf f16 [B][I] @0 (64MB) | xt f16 [I][B] @64M | ht f16 [H][B] @128M |
    //     wt f16 [H][I] @192M (2MB) | part f32 [16][I][H] @0 (overlaps dead xf)
    f16*   xf   = (f16*)(ws);
    f16*   xt   = (f16*)(ws + 67108864ull);
    f16*   ht   = (f16*)(ws + 134217728ull);
    f16*   wt   = (f16*)(ws + 201326592ull);
    float* part = (float*)(ws);

    k_prep<<<dim3(BB/64, II/64), 256, 0, stream>>>(x, xf, xt, II, BB);
    k_prep<<<dim3(II/64, HH/64), 256, 0, stream>>>(W, nullptr, wt, HH, II);
    k_gemm1t8<<<dim3((HH/256)*(BB/256)), 512, 0, stream>>>(wt, xf, hidden, ht);
    k_gemm2_8<<<dim3(16*SPLIT), 512, 0, stream>>>(xt, ht, part);
    k_final<<<dim3((II*HH)/1024), 256, 0, stream>>>(part, W, outW);
}

// Round 5
// 241.007 us; speedup vs baseline: 1.6171x; 1.1681x over previous
//
#include <hip/hip_runtime.h>
#include <cstdint>

#define BB 32768
#define II 1024
#define HH 1024
#define SPLIT 16
#define KCH (BB/SPLIT)      // 2048
#define NT1 (II/64)         // 16 K-tiles (gemm1)
#define NT2 (KCH/64)        // 32 K-tiles per split (gemm2)

typedef _Float16 f16;
typedef _Float16 f16x4 __attribute__((ext_vector_type(4)));
typedef _Float16 f16x8 __attribute__((ext_vector_type(8)));
typedef float f32x4 __attribute__((ext_vector_type(4)));

typedef const __attribute__((address_space(1))) void gvoid_t;
typedef __attribute__((address_space(3))) void lvoid_t;

__device__ __forceinline__ void gload16(const void* g, void* l){
    __builtin_amdgcn_global_load_lds((gvoid_t*)g, (lvoid_t*)l, 16, 0, 0);
}

__device__ __forceinline__ float tanh_fast(float s){
    float a = fabsf(s);
    float e = __expf(-2.0f * a);
    float t = __fdividef(1.0f - e, 1.0f + e);
    return s < 0.0f ? -t : t;
}

// in [R][C] f32 -> cvt_out [R][C] f16 (optional) + tr_out [C][R] f16. 64x64 tiles.
__global__ __launch_bounds__(256) void k_prep(const float* __restrict__ in,
                                              f16* __restrict__ cvt_out,
                                              f16* __restrict__ tr_out,
                                              int C, int R){
    __shared__ float lt[64*67];
    const int t = threadIdx.x;
    const int r0 = blockIdx.x*64, c0 = blockIdx.y*64;
    #pragma unroll
    for (int p=0; p<4; ++p){
        int r = p*16 + (t>>4);
        int c = (t&15)*4;
        float4 v = *(const float4*)&in[(size_t)(r0+r)*C + c0 + c];
        if (cvt_out){
            f16x4 hv = {(f16)v.x,(f16)v.y,(f16)v.z,(f16)v.w};
            *(f16x4*)&cvt_out[(size_t)(r0+r)*C + c0 + c] = hv;
        }
        lt[r*67 + c+0] = v.x;
        lt[r*67 + c+1] = v.y;
        lt[r*67 + c+2] = v.z;
        lt[r*67 + c+3] = v.w;
    }
    __syncthreads();
    const int c = t>>2, rb = (t&3)*16;
    f16x8 a, b;
    #pragma unroll
    for (int e=0; e<8; ++e) a[e] = (f16)lt[(rb+e)*67 + c];
    #pragma unroll
    for (int e=0; e<8; ++e) b[e] = (f16)lt[(rb+8+e)*67 + c];
    f16* o = &tr_out[(size_t)(c0+c)*R + r0 + rb];
    *(f16x8*)o = a;
    *(f16x8*)(o+8) = b;
}

// stage one 128x64-f16 half-tile (16KB) into linear LDS with inverse-swizzled source.
// Swizzle S(b): bits 4-6 ^= bits 7-9 (spreads each ds_read_b128 over all 32 banks).
__device__ __forceinline__ void stage_half(const f16* __restrict__ panel, int ld,
                                           int row0, int kcol0, char* lds_half,
                                           int wid, int lane){
    #pragma unroll
    for (int r=0;r<2;++r){
        int b  = r*8192 + wid*1024 + lane*16;
        int sb = b ^ ((lane & 0x38) << 1);
        const f16* src = panel + (size_t)(row0 + (sb>>7))*ld + kcol0 + ((sb&127)>>1);
        gload16(src, lds_half + r*8192 + wid*1024);
    }
}

#define RD_A(BUFA, mh) { \
    _Pragma("unroll") for (int m_=0;m_<4;++m_){ \
        af[m_][0] = *(const f16x8*)((BUFA) + rowA + (mh)*8192 + m_*2048 + ksw0); \
        af[m_][1] = *(const f16x8*)((BUFA) + rowA + (mh)*8192 + m_*2048 + ksw1); }}

#define RD_B(BUFB, nh) { \
    _Pragma("unroll") for (int n_=0;n_<2;++n_){ \
        bf[(nh)*2+n_][0] = *(const f16x8*)((BUFB) + rowB + (nh)*4096 + n_*2048 + ksw0); \
        bf[(nh)*2+n_][1] = *(const f16x8*)((BUFB) + rowB + (nh)*4096 + n_*2048 + ksw1); }}

#define MFMA_Q(mh,nh) { \
    __builtin_amdgcn_s_setprio(1); \
    _Pragma("unroll") for (int m_=0;m_<4;++m_){ \
      _Pragma("unroll") for (int n_=0;n_<2;++n_){ \
        _Pragma("unroll") for (int ks_=0;ks_<2;++ks_){ \
          acc[(mh)*4+m_][(nh)*2+n_] = __builtin_amdgcn_mfma_f32_16x16x32_f16( \
              af[m_][ks_], bf[(nh)*2+n_][ks_], acc[(mh)*4+m_][(nh)*2+n_], 0,0,0); }}} \
    __builtin_amdgcn_s_setprio(0); }

#define PH_SYNC1 { __builtin_amdgcn_s_barrier(); \
    asm volatile("s_waitcnt lgkmcnt(0)" ::: "memory"); \
    __builtin_amdgcn_sched_barrier(0); }
#define PH_SYNC2 { __builtin_amdgcn_s_barrier(); }

// 256x256 tile, BK=64, 8 waves, 8-phase pipelined K-loop (T2+T3+T4+T5).
__device__ __forceinline__ void kloop8(const f16* __restrict__ Ap, int lda, int arow0,
                                       const f16* __restrict__ Bp, int ldb, int brow0,
                                       int kbase, int nt, char* sm,
                                       f32x4 (&acc)[8][4])
{
    const int t = threadIdx.x, lane = t & 63, wid = t >> 6;
    const int wr = wid >> 2, wc = wid & 3;
    const int fr = lane & 15, kg = lane >> 4;
    const int mask = nt - 1;
    char* const A0 = sm;
    char* const B0 = sm + 32768;
    char* const A1 = sm + 65536;
    char* const B1 = sm + 98304;
    const int rowA = wr*16384 + fr*128;
    const int rowB = (wc>>1)*16384 + (wc&1)*8192 + fr*128;
    const int ksw0 = ((kg    ) ^ (fr & 7)) << 4;
    const int ksw1 = ((kg + 4) ^ (fr & 7)) << 4;

    f16x8 af[4][2], bf[4][2];

    // prologue: K0 -> buf0 (all 4 half-tiles), K1 -> B1 half0, A1 half0
    stage_half(Ap, lda, arow0 +   0, kbase +  0, A0,         wid, lane);
    stage_half(Ap, lda, arow0 + 128, kbase +  0, A0 + 16384, wid, lane);
    stage_half(Bp, ldb, brow0 +   0, kbase +  0, B0,         wid, lane);
    stage_half(Bp, ldb, brow0 + 128, kbase +  0, B0 + 16384, wid, lane);
    stage_half(Bp, ldb, brow0 +   0, kbase + 64, B1,         wid, lane);
    stage_half(Ap, lda, arow0 +   0, kbase + 64, A1,         wid, lane);
    asm volatile("s_waitcnt vmcnt(4)" ::: "memory");
    __builtin_amdgcn_s_barrier();

    const int ni = nt >> 1;
    for (int it = 0; it < ni; ++it){
        const int k1 = (2*it + 1) * 64;
        const int k2 = ((2*it + 2) & mask) * 64;
        const int k3 = ((2*it + 3) & mask) * 64;
        // phase 1: Q(0,0) from buf0; stage A1 half1 (k1)
        RD_A(A0, 0); RD_B(B0, 0);
        stage_half(Ap, lda, arow0 + 128, kbase + k1, A1 + 16384, wid, lane);
        PH_SYNC1; MFMA_Q(0,0); PH_SYNC2;
        // phase 2: Q(0,1); stage B1 half1 (k1)
        RD_B(B0, 1);
        stage_half(Bp, ldb, brow0 + 128, kbase + k1, B1 + 16384, wid, lane);
        PH_SYNC1; MFMA_Q(0,1); PH_SYNC2;
        // phase 3: Q(1,0); stage B0 half0 (k2)
        RD_A(A0, 1);
        stage_half(Bp, ldb, brow0 +   0, kbase + k2, B0, wid, lane);
        PH_SYNC1; MFMA_Q(1,0); PH_SYNC2;
        // phase 4: Q(1,1); stage A0 half0 (k2); counted vmcnt
        stage_half(Ap, lda, arow0 +   0, kbase + k2, A0, wid, lane);
        PH_SYNC1; MFMA_Q(1,1);
        asm volatile("s_waitcnt vmcnt(4)" ::: "memory");
        __builtin_amdgcn_s_barrier();
        // phase 5: Q(0,0) from buf1; stage A0 half1 (k2)
        RD_A(A1, 0); RD_B(B1, 0);
        stage_half(Ap, lda, arow0 + 128, kbase + k2, A0 + 16384, wid, lane);
        PH_SYNC1; MFMA_Q(0,0); PH_SYNC2;
        // phase 6: Q(0,1); stage B0 half1 (k2)
        RD_B(B1, 1);
        stage_half(Bp, ldb, brow0 + 128, kbase + k2, B0 + 16384, wid, lane);
        PH_SYNC1; MFMA_Q(0,1); PH_SYNC2;
        // phase 7: Q(1,0); stage B1 half0 (k3)
        RD_A(A1, 1);
        stage_half(Bp, ldb, brow0 +   0, kbase + k3, B1, wid, lane);
        PH_SYNC1; MFMA_Q(1,0); PH_SYNC2;
        // phase 8: Q(1,1); stage A1 half0 (k3); counted vmcnt
        stage_half(Ap, lda, arow0 +   0, kbase + k3, A1, wid, lane);
        PH_SYNC1; MFMA_Q(1,1);
        asm volatile("s_waitcnt vmcnt(4)" ::: "memory");
        __builtin_amdgcn_s_barrier();
    }
    asm volatile("s_waitcnt vmcnt(0)" ::: "memory");
    __builtin_amdgcn_s_barrier();
}

// GEMM1: D[b][h] = sum_i xf[b][i]*wt[h][i]; hidden[b][h]=tanh, ht[h][b]=f16(tanh).
// Epilogue: direct stores, no LDS. acc q-values = 4 consecutive b.
__global__ __launch_bounds__(512,2) void k_gemm1(const f16* __restrict__ xf,
                                                 const f16* __restrict__ wt,
                                                 float* __restrict__ hidden,
                                                 f16* __restrict__ ht){
    __shared__ char sm[131072];
    // XCD-bijective swizzle: nwg=512, 64/XCD -> each XCD: 16 consecutive btiles x 4 htiles
    const int bid = (int)blockIdx.x;
    const int swz = (bid & 7)*64 + (bid >> 3);
    const int btile = swz >> 2, htile = swz & 3;
    f32x4 acc[8][4] = {};
    kloop8(xf, II, btile*256, wt, II, htile*256, 0, NT1, sm, acc);

    const int t = threadIdx.x, lane = t & 63, wid = t >> 6;
    const int wr = wid >> 2, wc = wid & 3;
    const int fr = lane & 15, kg = lane >> 4;
    const int b_base = btile*256 + wr*128 + kg*4;
    const int h_base = htile*256 + wc*64 + fr;
    #pragma unroll
    for (int mf=0; mf<8; ++mf){
        const int b = b_base + mf*16;
        #pragma unroll
        for (int nf=0; nf<4; ++nf){
            const int h = h_base + nf*16;
            float t0 = tanh_fast(acc[mf][nf][0]);
            float t1 = tanh_fast(acc[mf][nf][1]);
            float t2 = tanh_fast(acc[mf][nf][2]);
            float t3 = tanh_fast(acc[mf][nf][3]);
            f16x4 hv = {(f16)t0,(f16)t1,(f16)t2,(f16)t3};
            *(f16x4*)&ht[(size_t)h*BB + b] = hv;
            hidden[(size_t)(b+0)*HH + h] = t0;
            hidden[(size_t)(b+1)*HH + h] = t1;
            hidden[(size_t)(b+2)*HH + h] = t2;
            hidden[(size_t)(b+3)*HH + h] = t3;
        }
    }
}

// GEMM2: part[split][i][h] (f16) = sum_{b in chunk} xt[i][b]*ht[h][b]
__global__ __launch_bounds__(512,2) void k_gemm2(const f16* __restrict__ xt,
                                                 const f16* __restrict__ ht,
                                                 f16* __restrict__ part){
    __shared__ char sm[131072];
    // nwg=256, 32/XCD -> each XCD: 2 full splits (8 panels on its own L2)
    const int bid = (int)blockIdx.x;
    const int swz = (bid & 7)*32 + (bid >> 3);
    const int split = swz >> 4, tile = swz & 15;
    const int itile = tile & 3, htile = tile >> 2;
    f32x4 acc[8][4] = {};
    kloop8(xt, BB, itile*256, ht, BB, htile*256, split*KCH, NT2, sm, acc);

    const int t = threadIdx.x, lane = t & 63, wid = t >> 6;
    const int wr = wid >> 2, wc = wid & 3;
    const int fr = lane & 15, kg = lane >> 4;
    const size_t pb = (size_t)split*II*HH;
    #pragma unroll
    for (int mf=0; mf<8; ++mf){
        const int i0 = itile*256 + wr*128 + mf*16 + kg*4;
        #pragma unroll
        for (int nf=0; nf<4; ++nf){
            const int h = htile*256 + wc*64 + nf*16 + fr;
            #pragma unroll
            for (int q=0;q<4;++q)
                part[pb + (size_t)(i0+q)*HH + h] = (f16)acc[mf][nf][q];
        }
    }
}

__global__ __launch_bounds__(256) void k_final(const f16* __restrict__ part,
                                               const float* __restrict__ W,
                                               float* __restrict__ outW){
    const int i = blockIdx.x*256 + threadIdx.x;
    const size_t o = (size_t)i*8;
    float s[8] = {};
    #pragma unroll
    for (int sp=0; sp<SPLIT; ++sp){
        f16x8 p = *(const f16x8*)&part[(size_t)sp*1048576 + o];
        #pragma unroll
        for (int e=0;e<8;++e) s[e] += (float)p[e];
    }
    const float SCALE = 3.0517578125e-07f;  // 0.01 / 32768
    #pragma unroll
    for (int j=0;j<2;++j){
        float4 w = *(const float4*)&W[o + j*4];
        float4 r;
        r.x = fminf(1.f, fmaxf(-1.f, fmaf(SCALE, s[j*4+0], w.x)));
        r.y = fminf(1.f, fmaxf(-1.f, fmaf(SCALE, s[j*4+1], w.y)));
        r.z = fminf(1.f, fmaxf(-1.f, fmaf(SCALE, s[j*4+2], w.z)));
        r.w = fminf(1.f, fmaxf(-1.f, fmaf(SCALE, s[j*4+3], w.w)));
        *(float4*)&outW[o + j*4] = r;
    }
}

extern "C" void kernel_launch(void* const* d_in, const int* in_sizes, int n_in,
                              void* d_out, int out_size, void* d_ws, size_t ws_size,
                              hipStream_t stream){
    (void)in_sizes; (void)n_in; (void)out_size; (void)ws_size;
    const float* x = (const float*)d_in[0];
    const float* W = (const float*)d_in[1];
    float* hidden = (float*)d_out;
    float* outW   = hidden + (size_t)BB*HH;
    char* ws = (char*)d_ws;
    // ws (194 MB, proven): xf f16 @0 (64MB) | xt f16 @64M | ht f16 @128M | wt f16 @192M (2MB)
    //                      part f16 [16][I][H] @0 (32MB, overlaps dead xf)
    f16* xf   = (f16*)(ws);
    f16* xt   = (f16*)(ws + 67108864ull);
    f16* ht   = (f16*)(ws + 134217728ull);
    f16* wt   = (f16*)(ws + 201326592ull);
    f16* part = (f16*)(ws);

    k_prep<<<dim3(BB/64, II/64), 256, 0, stream>>>(x, xf, xt, II, BB);
    k_prep<<<dim3(II/64, HH/64), 256, 0, stream>>>(W, nullptr, wt, HH, II);
    k_gemm1<<<dim3((BB/256)*(HH/256)), 512, 0, stream>>>(xf, wt, hidden, ht);
    k_gemm2<<<dim3(16*SPLIT), 512, 0, stream>>>(xt, ht, part);
    k_final<<<dim3((II*HH)/(256*8)), 256, 0, stream>>>(part, W, outW);
}

// Round 7
// 233.726 us; speedup vs baseline: 1.6675x; 1.0312x over previous
//
#include <hip/hip_runtime.h>
#include <cstdint>

#define BB 32768
#define II 1024
#define HH 1024
#define SPLIT 16
#define KCH (BB/SPLIT)      // 2048
#define NT1 (II/64)         // 16 K-tiles (gemm1)
#define NT2 (KCH/64)        // 32 K-tiles per split (gemm2)

typedef _Float16 f16;
typedef _Float16 f16x4 __attribute__((ext_vector_type(4)));
typedef _Float16 f16x8 __attribute__((ext_vector_type(8)));
typedef float f32x4 __attribute__((ext_vector_type(4)));

typedef const __attribute__((address_space(1))) void gvoid_t;
typedef __attribute__((address_space(3))) void lvoid_t;

__device__ __forceinline__ void gload16(const void* g, void* l){
    __builtin_amdgcn_global_load_lds((gvoid_t*)g, (lvoid_t*)l, 16, 0, 0);
}

__device__ __forceinline__ float tanh_fast(float s){
    float a = fabsf(s);
    float e = __expf(-2.0f * a);
    float t = __fdividef(1.0f - e, 1.0f + e);
    return s < 0.0f ? -t : t;
}

// in [R][C] f32 -> cvt_out [R][C] f16 (optional) + tr_out [C][R] f16. 64x64 tiles.
__global__ __launch_bounds__(256) void k_prep(const float* __restrict__ in,
                                              f16* __restrict__ cvt_out,
                                              f16* __restrict__ tr_out,
                                              int C, int R){
    __shared__ float lt[64*67];
    const int t = threadIdx.x;
    const int r0 = blockIdx.x*64, c0 = blockIdx.y*64;
    #pragma unroll
    for (int p=0; p<4; ++p){
        int r = p*16 + (t>>4);
        int c = (t&15)*4;
        float4 v = *(const float4*)&in[(size_t)(r0+r)*C + c0 + c];
        if (cvt_out){
            f16x4 hv = {(f16)v.x,(f16)v.y,(f16)v.z,(f16)v.w};
            *(f16x4*)&cvt_out[(size_t)(r0+r)*C + c0 + c] = hv;
        }
        lt[r*67 + c+0] = v.x;
        lt[r*67 + c+1] = v.y;
        lt[r*67 + c+2] = v.z;
        lt[r*67 + c+3] = v.w;
    }
    __syncthreads();
    const int c = t>>2, rb = (t&3)*16;
    f16x8 a, b;
    #pragma unroll
    for (int e=0; e<8; ++e) a[e] = (f16)lt[(rb+e)*67 + c];
    #pragma unroll
    for (int e=0; e<8; ++e) b[e] = (f16)lt[(rb+8+e)*67 + c];
    f16* o = &tr_out[(size_t)(c0+c)*R + r0 + rb];
    *(f16x8*)o = a;
    *(f16x8*)(o+8) = b;
}

// stage one 128x64-f16 half-tile (16KB) into linear LDS, source inverse-swizzled.
// LDS image byte b: row = b>>7, col c = (b&127) ^ (((b>>7)&7)<<4).
// MT=false: panel is flat [row][ld] k-major. MT=true: panel is 16x16 micro-tiled
// [h>>4][b>>4][h&15][b&15] f16 (256 elems / 512B per micro-tile).
template<bool MT>
__device__ __forceinline__ void stage_half(const f16* __restrict__ panel, int ld,
                                           int row0, int kcol0, char* lds_half,
                                           int wid, int lane){
    #pragma unroll
    for (int r=0;r<2;++r){
        int o = r*8192 + wid*1024 + lane*16;
        int rr = o>>7;
        int c0 = (o&127) ^ ((rr&7)<<4);
        if constexpr (!MT){
            const f16* src = panel + (size_t)(row0 + rr)*ld + kcol0 + (c0>>1);
            gload16(src, lds_half + r*8192 + wid*1024);
        } else {
            int h    = row0 + rr;
            int babs = kcol0 + (c0>>1);
            const f16* src = panel + (((size_t)(h>>4)*(BB>>4) + (babs>>4))<<8)
                                   + ((h&15)<<4) + (babs&8);
            gload16(src, lds_half + r*8192 + wid*1024);
        }
    }
}

#define RD_A(BUFA, mh) { \
    _Pragma("unroll") for (int m_=0;m_<4;++m_){ \
        af[m_][0] = *(const f16x8*)((BUFA) + rowA + (mh)*8192 + m_*2048 + ksw0); \
        af[m_][1] = *(const f16x8*)((BUFA) + rowA + (mh)*8192 + m_*2048 + ksw1); }}

#define RD_B(BUFB, nh) { \
    _Pragma("unroll") for (int n_=0;n_<2;++n_){ \
        bf[(nh)*2+n_][0] = *(const f16x8*)((BUFB) + rowB + (nh)*4096 + n_*2048 + ksw0); \
        bf[(nh)*2+n_][1] = *(const f16x8*)((BUFB) + rowB + (nh)*4096 + n_*2048 + ksw1); }}

#define MFMA_Q(mh,nh) { \
    __builtin_amdgcn_s_setprio(1); \
    _Pragma("unroll") for (int m_=0;m_<4;++m_){ \
      _Pragma("unroll") for (int n_=0;n_<2;++n_){ \
        _Pragma("unroll") for (int ks_=0;ks_<2;++ks_){ \
          acc[(mh)*4+m_][(nh)*2+n_] = __builtin_amdgcn_mfma_f32_16x16x32_f16( \
              af[m_][ks_], bf[(nh)*2+n_][ks_], acc[(mh)*4+m_][(nh)*2+n_], 0,0,0); }}} \
    __builtin_amdgcn_s_setprio(0); }

#define PH_SYNC1 { __builtin_amdgcn_s_barrier(); \
    asm volatile("s_waitcnt lgkmcnt(0)" ::: "memory"); \
    __builtin_amdgcn_sched_barrier(0); }
#define PH_SYNC2 { __builtin_amdgcn_s_barrier(); }

// 256x256 tile, BK=64, 8 waves, 8-phase pipelined K-loop (T2+T3+T4+T5).
template<bool BMT>
__device__ __forceinline__ void kloop8(const f16* __restrict__ Ap, int lda, int arow0,
                                       const f16* __restrict__ Bp, int ldb, int brow0,
                                       int kbase, int nt, char* sm,
                                       f32x4 (&acc)[8][4])
{
    const int t = threadIdx.x, lane = t & 63, wid = t >> 6;
    const int wr = wid >> 2, wc = wid & 3;
    const int fr = lane & 15, kg = lane >> 4;
    const int mask = nt - 1;
    char* const A0 = sm;
    char* const B0 = sm + 32768;
    char* const A1 = sm + 65536;
    char* const B1 = sm + 98304;
    const int rowA = wr*16384 + fr*128;
    const int rowB = (wc>>1)*16384 + (wc&1)*8192 + fr*128;
    const int ksw0 = ((kg    ) ^ (fr & 7)) << 4;
    const int ksw1 = ((kg + 4) ^ (fr & 7)) << 4;

    f16x8 af[4][2], bf[4][2];

    // prologue: K0 -> buf0 (all 4 half-tiles), K1 -> B1 half0, A1 half0
    stage_half<false>(Ap, lda, arow0 +   0, kbase +  0, A0,         wid, lane);
    stage_half<false>(Ap, lda, arow0 + 128, kbase +  0, A0 + 16384, wid, lane);
    stage_half<BMT  >(Bp, ldb, brow0 +   0, kbase +  0, B0,         wid, lane);
    stage_half<BMT  >(Bp, ldb, brow0 + 128, kbase +  0, B0 + 16384, wid, lane);
    stage_half<BMT  >(Bp, ldb, brow0 +   0, kbase + 64, B1,         wid, lane);
    stage_half<false>(Ap, lda, arow0 +   0, kbase + 64, A1,         wid, lane);
    asm volatile("s_waitcnt vmcnt(4)" ::: "memory");
    __builtin_amdgcn_s_barrier();

    const int ni = nt >> 1;
    for (int it = 0; it < ni; ++it){
        const int k1 = (2*it + 1) * 64;
        const int k2 = ((2*it + 2) & mask) * 64;
        const int k3 = ((2*it + 3) & mask) * 64;
        // phase 1: Q(0,0) from buf0; stage A1 half1 (k1)
        RD_A(A0, 0); RD_B(B0, 0);
        stage_half<false>(Ap, lda, arow0 + 128, kbase + k1, A1 + 16384, wid, lane);
        PH_SYNC1; MFMA_Q(0,0); PH_SYNC2;
        // phase 2: Q(0,1); stage B1 half1 (k1)
        RD_B(B0, 1);
        stage_half<BMT>(Bp, ldb, brow0 + 128, kbase + k1, B1 + 16384, wid, lane);
        PH_SYNC1; MFMA_Q(0,1); PH_SYNC2;
        // phase 3: Q(1,0); stage B0 half0 (k2)
        RD_A(A0, 1);
        stage_half<BMT>(Bp, ldb, brow0 +   0, kbase + k2, B0, wid, lane);
        PH_SYNC1; MFMA_Q(1,0); PH_SYNC2;
        // phase 4: Q(1,1); stage A0 half0 (k2); counted vmcnt
        stage_half<false>(Ap, lda, arow0 +   0, kbase + k2, A0, wid, lane);
        PH_SYNC1; MFMA_Q(1,1);
        asm volatile("s_waitcnt vmcnt(4)" ::: "memory");
        __builtin_amdgcn_s_barrier();
        // phase 5: Q(0,0) from buf1; stage A0 half1 (k2)
        RD_A(A1, 0); RD_B(B1, 0);
        stage_half<false>(Ap, lda, arow0 + 128, kbase + k2, A0 + 16384, wid, lane);
        PH_SYNC1; MFMA_Q(0,0); PH_SYNC2;
        // phase 6: Q(0,1); stage B0 half1 (k2)
        RD_B(B1, 1);
        stage_half<BMT>(Bp, ldb, brow0 + 128, kbase + k2, B0 + 16384, wid, lane);
        PH_SYNC1; MFMA_Q(0,1); PH_SYNC2;
        // phase 7: Q(1,0); stage B1 half0 (k3)
        RD_A(A1, 1);
        stage_half<BMT>(Bp, ldb, brow0 +   0, kbase + k3, B1, wid, lane);
        PH_SYNC1; MFMA_Q(1,0); PH_SYNC2;
        // phase 8: Q(1,1); stage A1 half0 (k3); counted vmcnt
        stage_half<false>(Ap, lda, arow0 +   0, kbase + k3, A1, wid, lane);
        PH_SYNC1; MFMA_Q(1,1);
        asm volatile("s_waitcnt vmcnt(4)" ::: "memory");
        __builtin_amdgcn_s_barrier();
    }
    asm volatile("s_waitcnt vmcnt(0)" ::: "memory");
    __builtin_amdgcn_s_barrier();
}

// GEMM1: D[b][h] = sum_i xf[b][i]*wt[h][i]; hidden[b][h]=tanh, ht=f16(tanh) micro-tiled.
__global__ __launch_bounds__(512,2) void k_gemm1(const f16* __restrict__ xf,
                                                 const f16* __restrict__ wt,
                                                 float* __restrict__ hidden,
                                                 f16* __restrict__ ht){
    __shared__ char sm[131072];
    // XCD-bijective swizzle: nwg=512, 64/XCD -> each XCD: 16 consecutive btiles x 4 htiles
    const int bid = (int)blockIdx.x;
    const int swz = (bid & 7)*64 + (bid >> 3);
    const int btile = swz >> 2, htile = swz & 3;
    f32x4 acc[8][4] = {};
    kloop8<false>(xf, II, btile*256, wt, II, htile*256, 0, NT1, sm, acc);

    const int t = threadIdx.x, lane = t & 63, wid = t >> 6;
    const int wr = wid >> 2, wc = wid & 3;
    const int fr = lane & 15, kg = lane >> 4;
    const int b_base = btile*256 + wr*128 + kg*4;
    const int h_base = htile*256 + wc*64 + fr;
    #pragma unroll
    for (int mf=0; mf<8; ++mf){
        const int b = b_base + mf*16;
        #pragma unroll
        for (int nf=0; nf<4; ++nf){
            const int h = h_base + nf*16;
            float t0 = tanh_fast(acc[mf][nf][0]);
            float t1 = tanh_fast(acc[mf][nf][1]);
            float t2 = tanh_fast(acc[mf][nf][2]);
            float t3 = tanh_fast(acc[mf][nf][3]);
            f16x4 hv = {(f16)t0,(f16)t1,(f16)t2,(f16)t3};
            // micro-tile store: one fully-contiguous 512B wave-store per fragment
            *(f16x4*)&ht[(((size_t)(h>>4)*(BB>>4) + (b>>4))<<8) + ((h&15)<<4) + (b&15)] = hv;
            hidden[(size_t)(b+0)*HH + h] = t0;
            hidden[(size_t)(b+1)*HH + h] = t1;
            hidden[(size_t)(b+2)*HH + h] = t2;
            hidden[(size_t)(b+3)*HH + h] = t3;
        }
    }
}

// GEMM2: part[split] = xt-chunk @ ht-chunk^T, part micro-tiled [i>>4][h>>4][h&15][i&15].
__global__ __launch_bounds__(512,2) void k_gemm2(const f16* __restrict__ xt,
                                                 const f16* __restrict__ ht,
                                                 f16* __restrict__ part){
    __shared__ char sm[131072];
    // nwg=256, 32/XCD -> each XCD: 2 full splits (panels on its own L2)
    const int bid = (int)blockIdx.x;
    const int swz = (bid & 7)*32 + (bid >> 3);
    const int split = swz >> 4, tile = swz & 15;
    const int itile = tile & 3, htile = tile >> 2;
    f32x4 acc[8][4] = {};
    kloop8<true>(xt, BB, itile*256, ht, BB, htile*256, split*KCH, NT2, sm, acc);

    const int t = threadIdx.x, lane = t & 63, wid = t >> 6;
    const int wr = wid >> 2, wc = wid & 3;
    const int fr = lane & 15, kg = lane >> 4;
    const size_t pb = (size_t)split*II*HH;
    #pragma unroll
    for (int mf=0; mf<8; ++mf){
        const int i0 = itile*256 + wr*128 + mf*16 + kg*4;
        #pragma unroll
        for (int nf=0; nf<4; ++nf){
            const int h = htile*256 + wc*64 + nf*16 + fr;
            f16x4 pv = {(f16)acc[mf][nf][0],(f16)acc[mf][nf][1],
                        (f16)acc[mf][nf][2],(f16)acc[mf][nf][3]};
            *(f16x4*)&part[pb + (((size_t)(i0>>4)*(HH>>4) + (h>>4))<<8) + ((h&15)<<4) + (i0&15)] = pv;
        }
    }
}

__global__ __launch_bounds__(256) void k_final(const f16* __restrict__ part,
                                               const float* __restrict__ W,
                                               float* __restrict__ outW){
    const int T = (int)blockIdx.x*256 + threadIdx.x;   // 0..131071
    const int mt = T >> 5;                             // micro-tile 0..4095 = (i>>4)*64+(h>>4)
    const int hl = (T & 31) >> 1;                      // 0..15
    const int ihalf = T & 1;
    const int i0 = (mt >> 6)*16 + ihalf*8;
    const int h  = (mt & 63)*16 + hl;
    const size_t po = ((size_t)mt << 8) + (hl << 4) + ihalf*8;
    float s[8] = {};
    #pragma unroll
    for (int sp=0; sp<SPLIT; ++sp){
        f16x8 p = *(const f16x8*)&part[(size_t)sp*1048576 + po];
        #pragma unroll
        for (int e=0;e<8;++e) s[e] += (float)p[e];
    }
    const float SCALE = 3.0517578125e-07f;  // 0.01 / 32768
    #pragma unroll
    for (int e=0;e<8;++e){
        const size_t o = (size_t)(i0+e)*HH + h;
        outW[o] = fminf(1.f, fmaxf(-1.f, fmaf(SCALE, s[e], W[o])));
    }
}

extern "C" void kernel_launch(void* const* d_in, const int* in_sizes, int n_in,
                              void* d_out, int out_size, void* d_ws, size_t ws_size,
                              hipStream_t stream){
    (void)in_sizes; (void)n_in; (void)out_size; (void)ws_size;
    const float* x = (const float*)d_in[0];
    const float* W = (const float*)d_in[1];
    float* hidden = (float*)d_out;
    float* outW   = hidden + (size_t)BB*HH;
    char* ws = (char*)d_ws;
    // ws (194 MB, proven): xf f16 @0 (64MB) | xt f16 @64M | ht f16 (micro) @128M | wt f16 @192M
    //                      part f16 [16][I][H] (micro) @0 (32MB, overlaps dead xf)
    f16* xf   = (f16*)(ws);
    f16* xt   = (f16*)(ws + 67108864ull);
    f16* ht   = (f16*)(ws + 134217728ull);
    f16* wt   = (f16*)(ws + 201326592ull);
    f16* part = (f16*)(ws);

    k_prep<<<dim3(BB/64, II/64), 256, 0, stream>>>(x, xf, xt, II, BB);
    k_prep<<<dim3(II/64, HH/64), 256, 0, stream>>>(W, nullptr, wt, HH, II);
    k_gemm1<<<dim3((BB/256)*(HH/256)), 512, 0, stream>>>(xf, wt, hidden, ht);
    k_gemm2<<<dim3(16*SPLIT), 512, 0, stream>>>(xt, ht, part);
    k_final<<<dim3((II*HH)/(256*8)), 256, 0, stream>>>(part, W, outW);
}